// Round 4
// baseline (211.337 us; speedup 1.0000x reference)
//
#include <hip/hip_runtime.h>
#include <hip/hip_bf16.h>

typedef __attribute__((ext_vector_type(8))) __bf16 bf16x8;
typedef __attribute__((ext_vector_type(4))) float f32x4;
typedef __attribute__((ext_vector_type(8))) unsigned short ushort8;
typedef unsigned short ushort;

__device__ __forceinline__ ushort f2bf(float f) {
    unsigned u = __builtin_bit_cast(unsigned, f);
    unsigned r = (u + 0x7fffu + ((u >> 16) & 1u)) >> 16;
    return (ushort)r;
}

__device__ __forceinline__ unsigned cvtpk(float a, float b) {
    unsigned r;
    asm("v_cvt_pk_bf16_f32 %0, %1, %2" : "=v"(r) : "v"(a), "v"(b));
    return r;
}

// ---------------------------------------------------------------------------
// Pack layer-1 weights (4x [512,256] fp32) and layer-2 weights into bf16
// MFMA-B-fragment order in ws. (unchanged)
// ---------------------------------------------------------------------------
__global__ __launch_bounds__(256) void k_pack(
    const float* __restrict__ w1a, const float* __restrict__ w1b,
    const float* __restrict__ w1c, const float* __restrict__ w1d,
    const float* __restrict__ w2a, const float* __restrict__ w2b,
    const float* __restrict__ w2c, const float* __restrict__ w2d,
    ushort* __restrict__ W1p, ushort* __restrict__ W2p)
{
    int c = blockIdx.x * 256 + threadIdx.x;
    if (c < 65536) {
        int l = c & 63, ks = (c >> 6) & 15, n16 = c >> 10;
        int j = n16 >> 4;
        int col = (n16 & 15) * 16 + (l & 15);
        int kb = ks * 32 + (l >> 4) * 8;
        const float* W = (j == 0) ? w1a : (j == 1) ? w1b : (j == 2) ? w1c : w1d;
        ushort8 o;
#pragma unroll
        for (int e = 0; e < 8; ++e) o[e] = f2bf(W[(size_t)(kb + e) * 256 + col]);
        *reinterpret_cast<ushort8*>(W1p + (size_t)c * 8) = o;
    } else if (c < 65536 + 10752) {
        int cc = c - 65536;
        int l = cc & 63, ks = (cc >> 6) & 7, f = cc >> 9;
        int colg = f * 16 + (l & 15);
        int kb = ks * 32 + (l >> 4) * 8;
        const float* W = nullptr; int lc = 0, ncols = 1;
        if (colg < 192)        { W = w2a; lc = colg;       ncols = 192; }
        else if (colg < 256)   { W = w2b; lc = colg - 192; ncols = 64; }
        else if (colg < 320)   { W = w2c; lc = colg - 256; ncols = 64; }
        else if (colg == 320)  { W = w2d; lc = 0;          ncols = 1; }
        ushort8 o;
#pragma unroll
        for (int e = 0; e < 8; ++e)
            o[e] = W ? f2bf(W[(size_t)(kb + e) * ncols + lc]) : (ushort)0;
        *reinterpret_cast<ushort8*>(W2p + (size_t)cc * 8) = o;
    }
}

// ---------------------------------------------------------------------------
// Layer-1 GEMM v3: block = 64 rows x 1024 cols, 512 threads = 8 waves.
// Wave w owns cols [w*128, w*128+128) (2 col-groups of 64). S staged once into
// 64 KB swizzled LDS; B-frags direct from L2-resident packed W1p.
// LDS 80 KB -> 2 blocks/CU -> 16 waves/CU (4/SIMD) for latency hiding.
// ---------------------------------------------------------------------------
__global__ __launch_bounds__(512, 4) void k_l1(
    const float* __restrict__ S, const ushort* __restrict__ W1p,
    const float* __restrict__ b0, const float* __restrict__ b1,
    const float* __restrict__ b2, const float* __restrict__ b3,
    ushort* __restrict__ hid, int m0)
{
    __shared__ ushort sA[64 * 512];     // 64 KB, 16B-granule XOR swizzle
    __shared__ ushort sT[8][64 * 16];   // 16 KB, per-wave transpose slice
    char* sAb = reinterpret_cast<char*>(sA);

    int tid = threadIdx.x, l = tid & 63, w = tid >> 6;  // w in 0..7
    int lr = l & 15, lg = l >> 4;
    int mt = blockIdx.x;
    const float* Srow = S + (size_t)(m0 + mt * 64) * 512;

    // ---- stage S[64][512] fp32 -> bf16, swizzled: addr16 = row*64 + (kc ^ (row&7))
#pragma unroll
    for (int i = 0; i < 8; ++i) {
        int c = i * 512 + tid;
        int row = c >> 6, kc = c & 63;
        const float4* g = reinterpret_cast<const float4*>(Srow + (size_t)row * 512 + kc * 8);
        float4 fa = g[0], fb = g[1];
        uint4 o;
        o.x = cvtpk(fa.x, fa.y); o.y = cvtpk(fa.z, fa.w);
        o.z = cvtpk(fb.x, fb.y); o.w = cvtpk(fb.z, fb.w);
        *reinterpret_cast<uint4*>(sAb + (size_t)(row * 64 + (kc ^ (row & 7))) * 16) = o;
    }
    __syncthreads();

    int j = w >> 1;
    const float* bp = (j == 0) ? b0 : (j == 1) ? b1 : (j == 2) ? b2 : b3;
    ushort* myT = sT[w];

    for (int cg = 0; cg < 2; ++cg) {
        f32x4 acc[4][4] = {{{0.f}}};
        for (int it = 0; it < 8; ++it) {
#pragma unroll
            for (int ks = 0; ks < 2; ++ks) {
                // B first (long-latency L2 loads), then A (LDS), then MFMA
                bf16x8 b[4];
#pragma unroll
                for (int nf = 0; nf < 4; ++nf) {
                    int n16 = w * 8 + cg * 4 + nf;
                    b[nf] = *reinterpret_cast<const bf16x8*>(
                        W1p + ((size_t)(n16 * 16 + it * 2 + ks) * 64 + l) * 8);
                }
                bf16x8 a[4];
#pragma unroll
                for (int mf = 0; mf < 4; ++mf) {
                    int row = mf * 16 + lr;
                    int kc = it * 8 + ks * 4 + lg;
                    a[mf] = *reinterpret_cast<const bf16x8*>(
                        sAb + (size_t)(row * 64 + (kc ^ (row & 7))) * 16);
                }
#pragma unroll
                for (int nf = 0; nf < 4; ++nf)
#pragma unroll
                    for (int mf = 0; mf < 4; ++mf)
                        acc[mf][nf] = __builtin_amdgcn_mfma_f32_16x16x32_bf16(
                            a[mf], b[nf], acc[mf][nf], 0, 0, 0);
            }
        }
        // ---- epilogue: bias+relu -> bf16, four 16-col slices via private LDS
        int colbase = w * 128 + cg * 64;
#pragma unroll
        for (int nf = 0; nf < 4; ++nf) {
            asm volatile("s_waitcnt lgkmcnt(0)" ::: "memory");  // WAR vs prior readback
            float bv = bp[(colbase + nf * 16 + lr) & 255];
#pragma unroll
            for (int mf = 0; mf < 4; ++mf)
#pragma unroll
                for (int r = 0; r < 4; ++r) {
                    float v = acc[mf][nf][r] + bv;
                    v = v > 0.f ? v : 0.f;
                    myT[(mf * 16 + lg * 4 + r) * 16 + lr] = f2bf(v);
                }
            asm volatile("s_waitcnt lgkmcnt(0)" ::: "memory");  // writes visible to self
#pragma unroll
            for (int jj = 0; jj < 2; ++jj) {
                int idx = jj * 64 + l;
                int row = idx >> 1, half = idx & 1;
                ushort8 o = *reinterpret_cast<const ushort8*>(myT + row * 16 + half * 8);
                *reinterpret_cast<ushort8*>(
                    hid + (size_t)(mt * 64 + row) * 1024 + colbase + nf * 16 + half * 8) = o;
            }
        }
    }
}

// ---------------------------------------------------------------------------
// Layer-2 (4 block GEMMs via MFMA) + mixer, fused. 32 samples / wg. (unchanged)
// ---------------------------------------------------------------------------
__global__ __launch_bounds__(256) void k_l2mix(
    const ushort* __restrict__ hid, const ushort* __restrict__ W2p,
    const float* __restrict__ bw1, const float* __restrict__ bb1,
    const float* __restrict__ bw2, const float* __restrict__ bb2,
    const float* __restrict__ q, float* __restrict__ out, int m0)
{
    __shared__ float sO[32 * 336];  // 43 KB
    int tid = threadIdx.x, l = tid & 63, w = tid >> 6;
    int lr = l & 15, lg = l >> 4;
    int sb = blockIdx.x * 32;

    const int fs[5] = {0, 6, 12, 17, 21};
    int jloaded = -1;
    bf16x8 a[2][8];
    for (int f = fs[w]; f < fs[w + 1]; ++f) {
        int j = (f < 12) ? 0 : (f < 16) ? 1 : (f < 20) ? 2 : 3;
        if (j != jloaded) {
#pragma unroll
            for (int mf = 0; mf < 2; ++mf)
#pragma unroll
                for (int ks = 0; ks < 8; ++ks)
                    a[mf][ks] = *reinterpret_cast<const bf16x8*>(
                        hid + (size_t)(sb + mf * 16 + lr) * 1024 + j * 256 + ks * 32 + lg * 8);
            jloaded = j;
        }
        f32x4 acc[2] = {};
#pragma unroll
        for (int ks = 0; ks < 8; ++ks) {
            bf16x8 b = *reinterpret_cast<const bf16x8*>(W2p + ((size_t)(f * 8 + ks) * 64 + l) * 8);
            acc[0] = __builtin_amdgcn_mfma_f32_16x16x32_bf16(a[0][ks], b, acc[0], 0, 0, 0);
            acc[1] = __builtin_amdgcn_mfma_f32_16x16x32_bf16(a[1][ks], b, acc[1], 0, 0, 0);
        }
        int colg = f * 16 + lr;
        float bv = 0.f; bool doabs = false;
        if (colg < 192)       { bv = bw1[colg];       doabs = true; }
        else if (colg < 256)  { bv = bb1[colg - 192]; doabs = false; }
        else if (colg < 320)  { bv = bw2[colg - 256]; doabs = true; }
        else if (colg == 320) { bv = bb2[0];          doabs = false; }
#pragma unroll
        for (int mf = 0; mf < 2; ++mf)
#pragma unroll
            for (int r = 0; r < 4; ++r) {
                float v = acc[mf][r] + bv;
                if (doabs) v = fabsf(v);
                sO[(mf * 16 + lg * 4 + r) * 336 + colg] = v;
            }
    }
    __syncthreads();

    // mixer: 8 threads per sample, each covers 8 of the 64 hidden units
    int sm = tid >> 3, oct = tid & 7;
    const float* qs = q + (size_t)(m0 + sb + sm) * 3;
    float q0 = qs[0], q1 = qs[1], q2 = qs[2];
    const float* ob = sO + sm * 336;
    float res[3];
#pragma unroll
    for (int n = 0; n < 3; ++n) {
        float qa, qb, qc;
        if (n == 0)      { qa = q0; qb = q1; qc = q2; }
        else if (n == 1) { qa = q1; qb = q0; qc = q2; }
        else             { qa = q2; qb = q0; qc = q1; }
        float accm = 0.f;
#pragma unroll
        for (int hh = 0; hh < 8; ++hh) {
            int hc = oct * 8 + hh;
            float hv = ob[192 + hc] + qa * ob[hc] + qb * ob[64 + hc] + qc * ob[128 + hc];
            float ev = hv > 0.f ? hv : expm1f(hv);
            accm += ev * ob[256 + hc];
        }
        accm += __shfl_xor(accm, 1);
        accm += __shfl_xor(accm, 2);
        accm += __shfl_xor(accm, 4);
        res[n] = accm;
    }
    if (oct == 0) {
        float b2v = ob[320];
        float* op = out + (size_t)(m0 + sb + sm) * 3;
        op[0] = res[0] + b2v;
        op[1] = res[1] + b2v;
        op[2] = res[2] + b2v;
    }
}

extern "C" void kernel_launch(void* const* d_in, const int* in_sizes, int n_in,
                              void* d_out, int out_size, void* d_ws, size_t ws_size,
                              hipStream_t stream)
{
    const float* q      = (const float*)d_in[0];
    const float* S      = (const float*)d_in[1];
    const float* hw1_W1 = (const float*)d_in[2];
    const float* hw1_b1 = (const float*)d_in[3];
    const float* hw1_W2 = (const float*)d_in[4];
    const float* hw1_b2 = (const float*)d_in[5];
    const float* hb1_W1 = (const float*)d_in[6];
    const float* hb1_b1 = (const float*)d_in[7];
    const float* hb1_W2 = (const float*)d_in[8];
    const float* hb1_b2 = (const float*)d_in[9];
    const float* hw2_W1 = (const float*)d_in[10];
    const float* hw2_b1 = (const float*)d_in[11];
    const float* hw2_W2 = (const float*)d_in[12];
    const float* hw2_b2 = (const float*)d_in[13];
    const float* hb2_W1 = (const float*)d_in[14];
    const float* hb2_b1 = (const float*)d_in[15];
    const float* hb2_W2 = (const float*)d_in[16];
    const float* hb2_b2 = (const float*)d_in[17];

    int TB = in_sizes[1] / 512;

    ushort* W1p = (ushort*)d_ws;            // 1 MB (65536 chunks * 16 B)
    ushort* W2p = W1p + (size_t)65536 * 8;  // 168 KB
    ushort* hid = W2p + (size_t)10752 * 8;
    size_t used = (size_t)(65536 + 10752) * 16;
    size_t hid_cap = (ws_size > used) ? (ws_size - used) : 0;
    long long max_chunk = (long long)(hid_cap / 2048);  // samples (1024 bf16 each)
    max_chunk &= ~127LL;
    if (max_chunk > TB) max_chunk = TB;
    if (max_chunk < 128) max_chunk = 128;  // best effort

    k_pack<<<dim3(298), dim3(256), 0, stream>>>(
        hw1_W1, hb1_W1, hw2_W1, hb2_W1,
        hw1_W2, hb1_W2, hw2_W2, hb2_W2, W1p, W2p);

    for (int m0 = 0; m0 < TB; m0 += (int)max_chunk) {
        int mc = TB - m0;
        if (mc > max_chunk) mc = (int)max_chunk;
        k_l1<<<dim3(mc / 64), dim3(512), 0, stream>>>(
            S, W1p, hw1_b1, hb1_b1, hw2_b1, hb2_b1, hid, m0);
        k_l2mix<<<dim3(mc / 32), dim3(256), 0, stream>>>(
            hid, W2p, hw1_b2, hb1_b2, hw2_b2, hb2_b2, q, (float*)d_out, m0);
    }
}

// Round 6
// 170.276 us; speedup vs baseline: 1.2411x; 1.2411x over previous
//
#include <hip/hip_runtime.h>
#include <hip/hip_bf16.h>

typedef __attribute__((ext_vector_type(8))) __bf16 bf16x8;
typedef __attribute__((ext_vector_type(4))) float f32x4;
typedef __attribute__((ext_vector_type(8))) unsigned short ushort8;
typedef unsigned short ushort;

__device__ __forceinline__ ushort f2bf(float f) {
    unsigned u = __builtin_bit_cast(unsigned, f);
    unsigned r = (u + 0x7fffu + ((u >> 16) & 1u)) >> 16;
    return (ushort)r;
}

__device__ __forceinline__ unsigned cvtpk(float a, float b) {
    unsigned r;
    asm("v_cvt_pk_bf16_f32 %0, %1, %2" : "=v"(r) : "v"(a), "v"(b));
    return r;
}

// ---------------------------------------------------------------------------
// Pack layer-1 weights (4x [512,256] fp32) and layer-2 weights into bf16
// MFMA-B-fragment order in ws. (unchanged)
// ---------------------------------------------------------------------------
__global__ __launch_bounds__(256) void k_pack(
    const float* __restrict__ w1a, const float* __restrict__ w1b,
    const float* __restrict__ w1c, const float* __restrict__ w1d,
    const float* __restrict__ w2a, const float* __restrict__ w2b,
    const float* __restrict__ w2c, const float* __restrict__ w2d,
    ushort* __restrict__ W1p, ushort* __restrict__ W2p)
{
    int c = blockIdx.x * 256 + threadIdx.x;
    if (c < 65536) {
        int l = c & 63, ks = (c >> 6) & 15, n16 = c >> 10;
        int j = n16 >> 4;
        int col = (n16 & 15) * 16 + (l & 15);
        int kb = ks * 32 + (l >> 4) * 8;
        const float* W = (j == 0) ? w1a : (j == 1) ? w1b : (j == 2) ? w1c : w1d;
        ushort8 o;
#pragma unroll
        for (int e = 0; e < 8; ++e) o[e] = f2bf(W[(size_t)(kb + e) * 256 + col]);
        *reinterpret_cast<ushort8*>(W1p + (size_t)c * 8) = o;
    } else if (c < 65536 + 10752) {
        int cc = c - 65536;
        int l = cc & 63, ks = (cc >> 6) & 7, f = cc >> 9;
        int colg = f * 16 + (l & 15);
        int kb = ks * 32 + (l >> 4) * 8;
        const float* W = nullptr; int lc = 0, ncols = 1;
        if (colg < 192)        { W = w2a; lc = colg;       ncols = 192; }
        else if (colg < 256)   { W = w2b; lc = colg - 192; ncols = 64; }
        else if (colg < 320)   { W = w2c; lc = colg - 256; ncols = 64; }
        else if (colg == 320)  { W = w2d; lc = 0;          ncols = 1; }
        ushort8 o;
#pragma unroll
        for (int e = 0; e < 8; ++e)
            o[e] = W ? f2bf(W[(size_t)(kb + e) * ncols + lc]) : (ushort)0;
        *reinterpret_cast<ushort8*>(W2p + (size_t)cc * 8) = o;
    }
}

// ---------------------------------------------------------------------------
// Layer-1 GEMM v4: R2 shape (64 rows x 1024 cols, 256 thr = 4 waves, wave w
// owns cols [w*256,(w+1)*256), 80 KB LDS -> 2 blocks/CU) + explicit register
// double-buffer for B-fragments at it-granularity (8 frags = 32 VGPR/buffer).
// B loads for it+1 are issued before consuming it; first it issued at kernel
// top so it overlaps the S->LDS staging phase.
// ---------------------------------------------------------------------------
__global__ __launch_bounds__(256) void k_l1(
    const float* __restrict__ S, const ushort* __restrict__ W1p,
    const float* __restrict__ b0, const float* __restrict__ b1,
    const float* __restrict__ b2, const float* __restrict__ b3,
    ushort* __restrict__ hid, int m0)
{
    __shared__ ushort sA[64 * 512];     // 64 KB, 16B-granule XOR swizzle
    __shared__ ushort sT[4][64 * 32];   // 16 KB, per-wave transpose slice
    char* sAb = reinterpret_cast<char*>(sA);

    int tid = threadIdx.x, l = tid & 63, w = tid >> 6;  // w in 0..3
    int lr = l & 15, lg = l >> 4;
    int mt = blockIdx.x;
    const float* Srow = S + (size_t)(m0 + mt * 64) * 512;

    bf16x8 bbuf[2][8];
    // issue B for (cg=0, it=0) immediately — flies during staging
    {
        const ushort* base = W1p + (size_t)(w * 16) * 16 * 64 * 8 + (size_t)l * 8;
#pragma unroll
        for (int ks = 0; ks < 2; ++ks)
#pragma unroll
            for (int nf = 0; nf < 4; ++nf)
                bbuf[0][ks * 4 + nf] = *reinterpret_cast<const bf16x8*>(
                    base + ((size_t)nf * 16 + ks) * 64 * 8);
    }

    // ---- stage S[64][512] fp32 -> bf16, swizzled: addr16 = row*64 + (kc ^ (row&7))
#pragma unroll
    for (int i = 0; i < 16; ++i) {
        int c = i * 256 + tid;
        int row = c >> 6, kc = c & 63;
        const float4* g = reinterpret_cast<const float4*>(Srow + (size_t)row * 512 + kc * 8);
        float4 fa = g[0], fb = g[1];
        uint4 o;
        o.x = cvtpk(fa.x, fa.y); o.y = cvtpk(fa.z, fa.w);
        o.z = cvtpk(fb.x, fb.y); o.w = cvtpk(fb.z, fb.w);
        *reinterpret_cast<uint4*>(sAb + (size_t)(row * 64 + (kc ^ (row & 7))) * 16) = o;
    }
    __syncthreads();

    const float* bp = (w == 0) ? b0 : (w == 1) ? b1 : (w == 2) ? b2 : b3;
    ushort* myT = sT[w];

    for (int cg = 0; cg < 4; ++cg) {
        f32x4 acc[4][4] = {{{0.f}}};
#pragma unroll
        for (int it = 0; it < 8; ++it) {
            // ---- issue B for next it (possibly next cg) into the other buffer
            {
                int nit = (it + 1) & 7;
                int ncg = (it == 7) ? cg + 1 : cg;
                if (ncg < 4) {
                    const ushort* base = W1p +
                        (((size_t)(w * 16 + ncg * 4) * 16 + (size_t)nit * 2) * 64 + l) * 8;
#pragma unroll
                    for (int ks = 0; ks < 2; ++ks)
#pragma unroll
                        for (int nf = 0; nf < 4; ++nf)
                            bbuf[(it + 1) & 1][ks * 4 + nf] =
                                *reinterpret_cast<const bf16x8*>(
                                    base + ((size_t)nf * 16 * 64 + (size_t)ks * 64) * 8);
                }
            }
            // ---- A fragments for both ks (8 ds_read_b128 issued together)
            bf16x8 a[2][4];
#pragma unroll
            for (int ks = 0; ks < 2; ++ks)
#pragma unroll
                for (int mf = 0; mf < 4; ++mf) {
                    int row = mf * 16 + lr;
                    int kc = it * 8 + ks * 4 + lg;
                    a[ks][mf] = *reinterpret_cast<const bf16x8*>(
                        sAb + (size_t)(row * 64 + (kc ^ (row & 7))) * 16);
                }
            // ---- MFMA: consume current buffer
#pragma unroll
            for (int ks = 0; ks < 2; ++ks)
#pragma unroll
                for (int nf = 0; nf < 4; ++nf)
#pragma unroll
                    for (int mf = 0; mf < 4; ++mf)
                        acc[mf][nf] = __builtin_amdgcn_mfma_f32_16x16x32_bf16(
                            a[ks][mf], bbuf[it & 1][ks * 4 + nf], acc[mf][nf], 0, 0, 0);
        }
        // ---- epilogue: bias+relu -> bf16, two 32-col halves via private slice
        int colbase = w * 256 + cg * 64;
        for (int h = 0; h < 2; ++h) {
            asm volatile("s_waitcnt lgkmcnt(0)" ::: "memory");  // WAR vs prior readback
#pragma unroll
            for (int nf2 = 0; nf2 < 2; ++nf2) {
                int nf = h * 2 + nf2;
                float bv = bp[(colbase + nf * 16 + lr) & 255];
#pragma unroll
                for (int mf = 0; mf < 4; ++mf)
#pragma unroll
                    for (int r = 0; r < 4; ++r) {
                        float v = acc[mf][nf][r] + bv;
                        v = v > 0.f ? v : 0.f;
                        myT[(mf * 16 + lg * 4 + r) * 32 + nf2 * 16 + lr] = f2bf(v);
                    }
            }
            asm volatile("s_waitcnt lgkmcnt(0)" ::: "memory");  // writes visible to self
#pragma unroll
            for (int i = 0; i < 4; ++i) {
                int idx = i * 64 + l;
                int row = idx >> 2, c8 = idx & 3;
                ushort8 o = *reinterpret_cast<const ushort8*>(myT + row * 32 + c8 * 8);
                *reinterpret_cast<ushort8*>(
                    hid + (size_t)(mt * 64 + row) * 1024 + colbase + h * 32 + c8 * 8) = o;
            }
        }
    }
}

// ---------------------------------------------------------------------------
// Layer-2 (4 block GEMMs via MFMA) + mixer, fused. 32 samples / wg. (unchanged)
// ---------------------------------------------------------------------------
__global__ __launch_bounds__(256) void k_l2mix(
    const ushort* __restrict__ hid, const ushort* __restrict__ W2p,
    const float* __restrict__ bw1, const float* __restrict__ bb1,
    const float* __restrict__ bw2, const float* __restrict__ bb2,
    const float* __restrict__ q, float* __restrict__ out, int m0)
{
    __shared__ float sO[32 * 336];  // 43 KB
    int tid = threadIdx.x, l = tid & 63, w = tid >> 6;
    int lr = l & 15, lg = l >> 4;
    int sb = blockIdx.x * 32;

    const int fs[5] = {0, 6, 12, 17, 21};
    int jloaded = -1;
    bf16x8 a[2][8];
    for (int f = fs[w]; f < fs[w + 1]; ++f) {
        int j = (f < 12) ? 0 : (f < 16) ? 1 : (f < 20) ? 2 : 3;
        if (j != jloaded) {
#pragma unroll
            for (int mf = 0; mf < 2; ++mf)
#pragma unroll
                for (int ks = 0; ks < 8; ++ks)
                    a[mf][ks] = *reinterpret_cast<const bf16x8*>(
                        hid + (size_t)(sb + mf * 16 + lr) * 1024 + j * 256 + ks * 32 + lg * 8);
            jloaded = j;
        }
        f32x4 acc[2] = {};
#pragma unroll
        for (int ks = 0; ks < 8; ++ks) {
            bf16x8 b = *reinterpret_cast<const bf16x8*>(W2p + ((size_t)(f * 8 + ks) * 64 + l) * 8);
            acc[0] = __builtin_amdgcn_mfma_f32_16x16x32_bf16(a[0][ks], b, acc[0], 0, 0, 0);
            acc[1] = __builtin_amdgcn_mfma_f32_16x16x32_bf16(a[1][ks], b, acc[1], 0, 0, 0);
        }
        int colg = f * 16 + lr;
        float bv = 0.f; bool doabs = false;
        if (colg < 192)       { bv = bw1[colg];       doabs = true; }
        else if (colg < 256)  { bv = bb1[colg - 192]; doabs = false; }
        else if (colg < 320)  { bv = bw2[colg - 256]; doabs = true; }
        else if (colg == 320) { bv = bb2[0];          doabs = false; }
#pragma unroll
        for (int mf = 0; mf < 2; ++mf)
#pragma unroll
            for (int r = 0; r < 4; ++r) {
                float v = acc[mf][r] + bv;
                if (doabs) v = fabsf(v);
                sO[(mf * 16 + lg * 4 + r) * 336 + colg] = v;
            }
    }
    __syncthreads();

    // mixer: 8 threads per sample, each covers 8 of the 64 hidden units
    int sm = tid >> 3, oct = tid & 7;
    const float* qs = q + (size_t)(m0 + sb + sm) * 3;
    float q0 = qs[0], q1 = qs[1], q2 = qs[2];
    const float* ob = sO + sm * 336;
    float res[3];
#pragma unroll
    for (int n = 0; n < 3; ++n) {
        float qa, qb, qc;
        if (n == 0)      { qa = q0; qb = q1; qc = q2; }
        else if (n == 1) { qa = q1; qb = q0; qc = q2; }
        else             { qa = q2; qb = q0; qc = q1; }
        float accm = 0.f;
#pragma unroll
        for (int hh = 0; hh < 8; ++hh) {
            int hc = oct * 8 + hh;
            float hv = ob[192 + hc] + qa * ob[hc] + qb * ob[64 + hc] + qc * ob[128 + hc];
            float ev = hv > 0.f ? hv : expm1f(hv);
            accm += ev * ob[256 + hc];
        }
        accm += __shfl_xor(accm, 1);
        accm += __shfl_xor(accm, 2);
        accm += __shfl_xor(accm, 4);
        res[n] = accm;
    }
    if (oct == 0) {
        float b2v = ob[320];
        float* op = out + (size_t)(m0 + sb + sm) * 3;
        op[0] = res[0] + b2v;
        op[1] = res[1] + b2v;
        op[2] = res[2] + b2v;
    }
}

extern "C" void kernel_launch(void* const* d_in, const int* in_sizes, int n_in,
                              void* d_out, int out_size, void* d_ws, size_t ws_size,
                              hipStream_t stream)
{
    const float* q      = (const float*)d_in[0];
    const float* S      = (const float*)d_in[1];
    const float* hw1_W1 = (const float*)d_in[2];
    const float* hw1_b1 = (const float*)d_in[3];
    const float* hw1_W2 = (const float*)d_in[4];
    const float* hw1_b2 = (const float*)d_in[5];
    const float* hb1_W1 = (const float*)d_in[6];
    const float* hb1_b1 = (const float*)d_in[7];
    const float* hb1_W2 = (const float*)d_in[8];
    const float* hb1_b2 = (const float*)d_in[9];
    const float* hw2_W1 = (const float*)d_in[10];
    const float* hw2_b1 = (const float*)d_in[11];
    const float* hw2_W2 = (const float*)d_in[12];
    const float* hw2_b2 = (const float*)d_in[13];
    const float* hb2_W1 = (const float*)d_in[14];
    const float* hb2_b1 = (const float*)d_in[15];
    const float* hb2_W2 = (const float*)d_in[16];
    const float* hb2_b2 = (const float*)d_in[17];

    int TB = in_sizes[1] / 512;

    ushort* W1p = (ushort*)d_ws;            // 1 MB (65536 chunks * 16 B)
    ushort* W2p = W1p + (size_t)65536 * 8;  // 168 KB
    ushort* hid = W2p + (size_t)10752 * 8;
    size_t used = (size_t)(65536 + 10752) * 16;
    size_t hid_cap = (ws_size > used) ? (ws_size - used) : 0;
    long long max_chunk = (long long)(hid_cap / 2048);  // samples (1024 bf16 each)
    max_chunk &= ~127LL;
    if (max_chunk > TB) max_chunk = TB;
    if (max_chunk < 128) max_chunk = 128;  // best effort

    k_pack<<<dim3(298), dim3(256), 0, stream>>>(
        hw1_W1, hb1_W1, hw2_W1, hb2_W1,
        hw1_W2, hb1_W2, hw2_W2, hb2_W2, W1p, W2p);

    for (int m0 = 0; m0 < TB; m0 += (int)max_chunk) {
        int mc = TB - m0;
        if (mc > max_chunk) mc = (int)max_chunk;
        k_l1<<<dim3(mc / 64), dim3(256), 0, stream>>>(
            S, W1p, hw1_b1, hb1_b1, hw2_b1, hb2_b1, hid, m0);
        k_l2mix<<<dim3(mc / 32), dim3(256), 0, stream>>>(
            hid, W2p, hw1_b2, hb1_b2, hw2_b2, hb2_b2, q, (float*)d_out, m0);
    }
}

// Round 7
// 165.885 us; speedup vs baseline: 1.2740x; 1.0265x over previous
//
#include <hip/hip_runtime.h>
#include <hip/hip_bf16.h>

typedef __attribute__((ext_vector_type(8))) __bf16 bf16x8;
typedef __attribute__((ext_vector_type(4))) float f32x4;
typedef __attribute__((ext_vector_type(8))) unsigned short ushort8;
typedef unsigned short ushort;

__device__ __forceinline__ ushort f2bf(float f) {
    unsigned u = __builtin_bit_cast(unsigned, f);
    unsigned r = (u + 0x7fffu + ((u >> 16) & 1u)) >> 16;
    return (ushort)r;
}

__device__ __forceinline__ unsigned cvtpk(float a, float b) {
    unsigned r;
    asm("v_cvt_pk_bf16_f32 %0, %1, %2" : "=v"(r) : "v"(a), "v"(b));
    return r;
}

// ---------------------------------------------------------------------------
// Pack layer-1 weights (4x [512,256] fp32) and layer-2 weights into bf16
// MFMA-B-fragment order in ws. (unchanged)
// W1p ushort offset = w*131072 + cg*32768 + nf*8192 + it*1024 + ks*512 + l*8
// ---------------------------------------------------------------------------
__global__ __launch_bounds__(256) void k_pack(
    const float* __restrict__ w1a, const float* __restrict__ w1b,
    const float* __restrict__ w1c, const float* __restrict__ w1d,
    const float* __restrict__ w2a, const float* __restrict__ w2b,
    const float* __restrict__ w2c, const float* __restrict__ w2d,
    ushort* __restrict__ W1p, ushort* __restrict__ W2p)
{
    int c = blockIdx.x * 256 + threadIdx.x;
    if (c < 65536) {
        int l = c & 63, ks = (c >> 6) & 15, n16 = c >> 10;
        int j = n16 >> 4;
        int col = (n16 & 15) * 16 + (l & 15);
        int kb = ks * 32 + (l >> 4) * 8;
        const float* W = (j == 0) ? w1a : (j == 1) ? w1b : (j == 2) ? w1c : w1d;
        ushort8 o;
#pragma unroll
        for (int e = 0; e < 8; ++e) o[e] = f2bf(W[(size_t)(kb + e) * 256 + col]);
        *reinterpret_cast<ushort8*>(W1p + (size_t)c * 8) = o;
    } else if (c < 65536 + 10752) {
        int cc = c - 65536;
        int l = cc & 63, ks = (cc >> 6) & 7, f = cc >> 9;
        int colg = f * 16 + (l & 15);
        int kb = ks * 32 + (l >> 4) * 8;
        const float* W = nullptr; int lc = 0, ncols = 1;
        if (colg < 192)        { W = w2a; lc = colg;       ncols = 192; }
        else if (colg < 256)   { W = w2b; lc = colg - 192; ncols = 64; }
        else if (colg < 320)   { W = w2c; lc = colg - 256; ncols = 64; }
        else if (colg == 320)  { W = w2d; lc = 0;          ncols = 1; }
        ushort8 o;
#pragma unroll
        for (int e = 0; e < 8; ++e)
            o[e] = W ? f2bf(W[(size_t)(kb + e) * ncols + lc]) : (ushort)0;
        *reinterpret_cast<ushort8*>(W2p + (size_t)cc * 8) = o;
    }
}

// ---------------------------------------------------------------------------
// Layer-1 GEMM v5: 64 rows x 1024 cols, 256 thr = 4 waves, wave w owns cols
// [w*256,(w+1)*256). Fully-unrolled 32-step K/cg sequence with a 3-deep
// register ring for B (prefetch distance 2 steps ~ 1500 cyc), sched_barrier
// pinning the issue point at region top. Epilogue: no asm fences (per-wave
// LDS is in-order; compiler tracks deps), nf-quarter tiles, stride-20 sT
// (lg-groups on disjoint bank octets). LDS 74 KB -> 2 blocks/CU.
// ---------------------------------------------------------------------------
__global__ __launch_bounds__(256) void k_l1(
    const float* __restrict__ S, const ushort* __restrict__ W1p,
    const float* __restrict__ b0, const float* __restrict__ b1,
    const float* __restrict__ b2, const float* __restrict__ b3,
    ushort* __restrict__ hid, int m0)
{
    __shared__ ushort sA[64 * 512];     // 64 KB, 16B-granule XOR swizzle
    __shared__ ushort sT[4][64 * 20];   // 10 KB, per-wave transpose slice
    char* sAb = reinterpret_cast<char*>(sA);

    int tid = threadIdx.x, l = tid & 63, w = tid >> 6;  // w in 0..3
    int lr = l & 15, lg = l >> 4;
    int mt = blockIdx.x;
    const float* Srow = S + (size_t)(m0 + mt * 64) * 512;

    // per-wave packed-B base; per-(cg,nf,it,ks) offsets are compile-time
    const ushort* Wb = W1p + (size_t)w * 131072 + (size_t)l * 8;

    bf16x8 ring[3][8];
    // prologue: issue steps 0 and 1 -> ring[0], ring[1]; they fly during staging
#pragma unroll
    for (int p = 0; p < 2; ++p)
#pragma unroll
        for (int ks = 0; ks < 2; ++ks)
#pragma unroll
            for (int nf = 0; nf < 4; ++nf)
                ring[p][ks * 4 + nf] = *reinterpret_cast<const bf16x8*>(
                    Wb + nf * 8192 + p * 1024 + ks * 512);

    // ---- stage S[64][512] fp32 -> bf16, swizzled: addr16 = row*64 + (kc ^ (row&7))
#pragma unroll
    for (int i = 0; i < 16; ++i) {
        int c = i * 256 + tid;
        int row = c >> 6, kc = c & 63;
        const float4* g = reinterpret_cast<const float4*>(Srow + (size_t)row * 512 + kc * 8);
        float4 fa = g[0], fb = g[1];
        uint4 o;
        o.x = cvtpk(fa.x, fa.y); o.y = cvtpk(fa.z, fa.w);
        o.z = cvtpk(fb.x, fb.y); o.w = cvtpk(fb.z, fb.w);
        *reinterpret_cast<uint4*>(sAb + (size_t)(row * 64 + (kc ^ (row & 7))) * 16) = o;
    }
    __syncthreads();

    const float* bp = (w == 0) ? b0 : (w == 1) ? b1 : (w == 2) ? b2 : b3;
    ushort* myT = sT[w];

#pragma unroll
    for (int cg = 0; cg < 4; ++cg) {
        f32x4 acc[4][4] = {{{0.f}}};
#pragma unroll
        for (int it = 0; it < 8; ++it) {
            const int s = cg * 8 + it;
            // ---- issue B for step s+2 into ring[(s+2)%3] (dist-2 prefetch)
            if (s + 2 < 32) {
                const int s2 = s + 2, cg2 = s2 >> 3, it2 = s2 & 7;
#pragma unroll
                for (int ks = 0; ks < 2; ++ks)
#pragma unroll
                    for (int nf = 0; nf < 4; ++nf)
                        ring[s2 % 3][ks * 4 + nf] = *reinterpret_cast<const bf16x8*>(
                            Wb + cg2 * 32768 + nf * 8192 + it2 * 1024 + ks * 512);
            }
            __builtin_amdgcn_sched_barrier(0);  // pin issue point at region top
            // ---- A fragments (8 ds_read_b128)
            bf16x8 a[2][4];
#pragma unroll
            for (int ks = 0; ks < 2; ++ks)
#pragma unroll
                for (int mf = 0; mf < 4; ++mf) {
                    int row = mf * 16 + lr;
                    int kc = it * 8 + ks * 4 + lg;
                    a[ks][mf] = *reinterpret_cast<const bf16x8*>(
                        sAb + (size_t)(row * 64 + (kc ^ (row & 7))) * 16);
                }
            // ---- MFMA: consume ring[s%3] (loaded 2 steps ago -> no vm wait)
#pragma unroll
            for (int ks = 0; ks < 2; ++ks)
#pragma unroll
                for (int nf = 0; nf < 4; ++nf)
#pragma unroll
                    for (int mf = 0; mf < 4; ++mf)
                        acc[mf][nf] = __builtin_amdgcn_mfma_f32_16x16x32_bf16(
                            a[ks][mf], ring[s % 3][ks * 4 + nf], acc[mf][nf], 0, 0, 0);
        }
        // ---- epilogue: bias+relu -> bf16, nf-quarter tiles via private slice
        int colbase = w * 256 + cg * 64;
#pragma unroll
        for (int nf = 0; nf < 4; ++nf) {
            float bv = bp[(colbase + nf * 16 + lr) & 255];
#pragma unroll
            for (int mf = 0; mf < 4; ++mf)
#pragma unroll
                for (int r = 0; r < 4; ++r) {
                    float v = acc[mf][nf][r] + bv;
                    v = v > 0.f ? v : 0.f;
                    myT[(mf * 16 + lg * 4 + r) * 20 + lr] = f2bf(v);
                }
#pragma unroll
            for (int i = 0; i < 2; ++i) {
                int idx = i * 64 + l;
                int row = idx >> 1, half = idx & 1;
                ushort8 o = *reinterpret_cast<const ushort8*>(myT + row * 20 + half * 8);
                *reinterpret_cast<ushort8*>(
                    hid + (size_t)(mt * 64 + row) * 1024 + colbase + nf * 16 + half * 8) = o;
            }
        }
    }
}

// ---------------------------------------------------------------------------
// Layer-2 (4 block GEMMs via MFMA) + mixer, fused. 32 samples / wg. (unchanged)
// ---------------------------------------------------------------------------
__global__ __launch_bounds__(256) void k_l2mix(
    const ushort* __restrict__ hid, const ushort* __restrict__ W2p,
    const float* __restrict__ bw1, const float* __restrict__ bb1,
    const float* __restrict__ bw2, const float* __restrict__ bb2,
    const float* __restrict__ q, float* __restrict__ out, int m0)
{
    __shared__ float sO[32 * 336];  // 43 KB
    int tid = threadIdx.x, l = tid & 63, w = tid >> 6;
    int lr = l & 15, lg = l >> 4;
    int sb = blockIdx.x * 32;

    const int fs[5] = {0, 6, 12, 17, 21};
    int jloaded = -1;
    bf16x8 a[2][8];
    for (int f = fs[w]; f < fs[w + 1]; ++f) {
        int j = (f < 12) ? 0 : (f < 16) ? 1 : (f < 20) ? 2 : 3;
        if (j != jloaded) {
#pragma unroll
            for (int mf = 0; mf < 2; ++mf)
#pragma unroll
                for (int ks = 0; ks < 8; ++ks)
                    a[mf][ks] = *reinterpret_cast<const bf16x8*>(
                        hid + (size_t)(sb + mf * 16 + lr) * 1024 + j * 256 + ks * 32 + lg * 8);
            jloaded = j;
        }
        f32x4 acc[2] = {};
#pragma unroll
        for (int ks = 0; ks < 8; ++ks) {
            bf16x8 b = *reinterpret_cast<const bf16x8*>(W2p + ((size_t)(f * 8 + ks) * 64 + l) * 8);
            acc[0] = __builtin_amdgcn_mfma_f32_16x16x32_bf16(a[0][ks], b, acc[0], 0, 0, 0);
            acc[1] = __builtin_amdgcn_mfma_f32_16x16x32_bf16(a[1][ks], b, acc[1], 0, 0, 0);
        }
        int colg = f * 16 + lr;
        float bv = 0.f; bool doabs = false;
        if (colg < 192)       { bv = bw1[colg];       doabs = true; }
        else if (colg < 256)  { bv = bb1[colg - 192]; doabs = false; }
        else if (colg < 320)  { bv = bw2[colg - 256]; doabs = true; }
        else if (colg == 320) { bv = bb2[0];          doabs = false; }
#pragma unroll
        for (int mf = 0; mf < 2; ++mf)
#pragma unroll
            for (int r = 0; r < 4; ++r) {
                float v = acc[mf][r] + bv;
                if (doabs) v = fabsf(v);
                sO[(mf * 16 + lg * 4 + r) * 336 + colg] = v;
            }
    }
    __syncthreads();

    // mixer: 8 threads per sample, each covers 8 of the 64 hidden units
    int sm = tid >> 3, oct = tid & 7;
    const float* qs = q + (size_t)(m0 + sb + sm) * 3;
    float q0 = qs[0], q1 = qs[1], q2 = qs[2];
    const float* ob = sO + sm * 336;
    float res[3];
#pragma unroll
    for (int n = 0; n < 3; ++n) {
        float qa, qb, qc;
        if (n == 0)      { qa = q0; qb = q1; qc = q2; }
        else if (n == 1) { qa = q1; qb = q0; qc = q2; }
        else             { qa = q2; qb = q0; qc = q1; }
        float accm = 0.f;
#pragma unroll
        for (int hh = 0; hh < 8; ++hh) {
            int hc = oct * 8 + hh;
            float hv = ob[192 + hc] + qa * ob[hc] + qb * ob[64 + hc] + qc * ob[128 + hc];
            float ev = hv > 0.f ? hv : expm1f(hv);
            accm += ev * ob[256 + hc];
        }
        accm += __shfl_xor(accm, 1);
        accm += __shfl_xor(accm, 2);
        accm += __shfl_xor(accm, 4);
        res[n] = accm;
    }
    if (oct == 0) {
        float b2v = ob[320];
        float* op = out + (size_t)(m0 + sb + sm) * 3;
        op[0] = res[0] + b2v;
        op[1] = res[1] + b2v;
        op[2] = res[2] + b2v;
    }
}

extern "C" void kernel_launch(void* const* d_in, const int* in_sizes, int n_in,
                              void* d_out, int out_size, void* d_ws, size_t ws_size,
                              hipStream_t stream)
{
    const float* q      = (const float*)d_in[0];
    const float* S      = (const float*)d_in[1];
    const float* hw1_W1 = (const float*)d_in[2];
    const float* hw1_b1 = (const float*)d_in[3];
    const float* hw1_W2 = (const float*)d_in[4];
    const float* hw1_b2 = (const float*)d_in[5];
    const float* hb1_W1 = (const float*)d_in[6];
    const float* hb1_b1 = (const float*)d_in[7];
    const float* hb1_W2 = (const float*)d_in[8];
    const float* hb1_b2 = (const float*)d_in[9];
    const float* hw2_W1 = (const float*)d_in[10];
    const float* hw2_b1 = (const float*)d_in[11];
    const float* hw2_W2 = (const float*)d_in[12];
    const float* hw2_b2 = (const float*)d_in[13];
    const float* hb2_W1 = (const float*)d_in[14];
    const float* hb2_b1 = (const float*)d_in[15];
    const float* hb2_W2 = (const float*)d_in[16];
    const float* hb2_b2 = (const float*)d_in[17];

    int TB = in_sizes[1] / 512;

    ushort* W1p = (ushort*)d_ws;            // 1 MB (65536 chunks * 16 B)
    ushort* W2p = W1p + (size_t)65536 * 8;  // 168 KB
    ushort* hid = W2p + (size_t)10752 * 8;
    size_t used = (size_t)(65536 + 10752) * 16;
    size_t hid_cap = (ws_size > used) ? (ws_size - used) : 0;
    long long max_chunk = (long long)(hid_cap / 2048);  // samples (1024 bf16 each)
    max_chunk &= ~127LL;
    if (max_chunk > TB) max_chunk = TB;
    if (max_chunk < 128) max_chunk = 128;  // best effort

    k_pack<<<dim3(298), dim3(256), 0, stream>>>(
        hw1_W1, hb1_W1, hw2_W1, hb2_W1,
        hw1_W2, hb1_W2, hw2_W2, hb2_W2, W1p, W2p);

    for (int m0 = 0; m0 < TB; m0 += (int)max_chunk) {
        int mc = TB - m0;
        if (mc > max_chunk) mc = (int)max_chunk;
        k_l1<<<dim3(mc / 64), dim3(256), 0, stream>>>(
            S, W1p, hw1_b1, hb1_b1, hw2_b1, hb2_b1, hid, m0);
        k_l2mix<<<dim3(mc / 32), dim3(256), 0, stream>>>(
            hid, W2p, hw1_b2, hb1_b2, hw2_b2, hb2_b2, q, (float*)d_out, m0);
    }
}